// Round 2
// baseline (141.878 us; speedup 1.0000x reference)
//
#include <hip/hip_runtime.h>

// ---- problem constants ----
#define HOP 160
#define NROWS 402            // 2*CUT
#define NTAPS 400            // N_FFT
#define T_SIG 9600000
#define N_FRAMES 60001
#define PAD 200              // CUT-1

// ---- tiling ----
#define MT 13                // 13 m-tiles * 32 rows = 416 (rows padded)
#define KS 26                // 26 k-steps * 16 taps = 416 (taps padded)
#define FPB 64               // frames per block
#define THREADS 512          // 8 waves: (frame-half, m-quarter)
#define SPAN (63*HOP + 416)  // 10496 signal floats staged per block
#define SPAN4 (SPAN/4)       // 2624
#define LDSE 11024           // padded bf16 elems: 10496 + 8 per 160 block (max pos 11015)

typedef __bf16 bf16x8 __attribute__((ext_vector_type(8)));
typedef float f32x16 __attribute__((ext_vector_type(16)));
typedef unsigned short u16x8 __attribute__((ext_vector_type(8)));
typedef unsigned short u16x4 __attribute__((ext_vector_type(4)));

__device__ __forceinline__ unsigned short f2bf(float f) {
    unsigned int u = __builtin_bit_cast(unsigned int, f);
    u += 0x7fffu + ((u >> 16) & 1u);
    return (unsigned short)(u >> 16);
}

// Pack basis fp32[402][400] -> bf16 in per-fragment lane order:
// packed[((mt*KS+ks)*64 + lane)*8 + i] = bf16(basis[mt*32+(lane&31)][ks*16+8*(lane>>5)+i])
__global__ void stft_prep(const float* __restrict__ basis,
                          unsigned short* __restrict__ packed) {
    int tid = blockIdx.x * 256 + threadIdx.x;
    if (tid >= MT * KS * 64) return;
    int lane = tid & 63;
    int frag = tid >> 6;
    int ks = frag % KS;
    int mt = frag / KS;
    int row = mt * 32 + (lane & 31);
    int colb = ks * 16 + (lane >> 5) * 8;
    u16x8 v;
#pragma unroll
    for (int i = 0; i < 8; ++i) {
        int col = colb + i;
        float f = (row < NROWS && col < NTAPS) ? basis[row * NTAPS + col] : 0.0f;
        v[i] = f2bf(f);
    }
    *reinterpret_cast<u16x8*>(packed + (size_t)tid * 8) = v;
}

// C[row][t] = sum_c basis[row][c] * sig[t*160 + c - 200]
// 8 waves/block: wave w -> frame-half (w&1)*32, m-quarter w>>1.
// One barrier total; waves stream independently afterwards.
__launch_bounds__(THREADS, 6)
__global__ void stft_mfma(const float* __restrict__ sig,
                          const unsigned short* __restrict__ packedA,
                          float* __restrict__ out) {
    __shared__ unsigned short sl[LDSE];
    const int tid = threadIdx.x;
    const int bid = blockIdx.x;
    const long sbase = (long)bid * (FPB * HOP) - PAD;

    // stage signal span -> bf16 LDS (coalesced float4, edge-guarded)
    for (int idx = tid; idx < SPAN4; idx += THREADS) {
        const int e = idx * 4;
        const long g0 = sbase + e;
        float4 v;
        if (g0 >= 0 && g0 + 4 <= (long)T_SIG) {
            v = *reinterpret_cast<const float4*>(sig + g0);
        } else {
            v.x = (g0 + 0 >= 0 && g0 + 0 < (long)T_SIG) ? sig[g0 + 0] : 0.0f;
            v.y = (g0 + 1 >= 0 && g0 + 1 < (long)T_SIG) ? sig[g0 + 1] : 0.0f;
            v.z = (g0 + 2 >= 0 && g0 + 2 < (long)T_SIG) ? sig[g0 + 2] : 0.0f;
            v.w = (g0 + 3 >= 0 && g0 + 3 < (long)T_SIG) ? sig[g0 + 3] : 0.0f;
        }
        u16x4 s;
        s[0] = f2bf(v.x); s[1] = f2bf(v.y); s[2] = f2bf(v.z); s[3] = f2bf(v.w);
        const int pos = e + 8 * (e / 160);  // 4-chunk never crosses a 160 block
        *reinterpret_cast<u16x4*>(&sl[pos]) = s;
    }
    __syncthreads();

    const int lane = tid & 63;
    const int w = tid >> 6;        // wave id
    const int l31 = lane & 31;
    const int g = lane >> 5;       // k-group
    const int fg = w & 1;          // frame half
    const int mh = w >> 1;         // m quarter
    const int lf = fg * 32 + l31;  // local frame 0..63
    const long t = (long)bid * FPB + lf;

    // wave's m-tiles: {0..3},{4..6},{7..9},{10..12}
    const int mt0 = (mh == 0) ? 0 : 3 * mh + 1;
    const int mtN = (mh == 0) ? 4 : 3;

    // B-frag LDS base: 8 contiguous bf16 at lf*168 + g*8 + (ks*16 + 8*(ks/10))
    const unsigned short* bbase = &sl[lf * 168 + g * 8];
    const int rowg = 4 * g;

    for (int mi = 0; mi < mtN; ++mi) {
        const int mt = mt0 + mi;
        f32x16 acc = {0,0,0,0,0,0,0,0,0,0,0,0,0,0,0,0};
        const unsigned short* pA = packedA + ((size_t)(mt * KS) * 64 + lane) * 8;
#pragma unroll
        for (int ks = 0; ks < KS; ++ks) {
            const bf16x8 a = *reinterpret_cast<const bf16x8*>(pA + (size_t)ks * 64 * 8);
            const bf16x8 b = *reinterpret_cast<const bf16x8*>(bbase + ks * 16 + 8 * (ks / 10));
            acc = __builtin_amdgcn_mfma_f32_32x32x16_bf16(a, b, acc, 0, 0, 0);
        }
        if (t < N_FRAMES) {
            const int rb = mt * 32 + rowg;
#pragma unroll
            for (int r = 0; r < 16; ++r) {
                // C/D map: row=(r&3)+8*(r>>2)+4*(lane>>5), col=lane&31
                const int row = rb + (r & 3) + 8 * (r >> 2);
                if (row < NROWS) out[(long)row * N_FRAMES + t] = acc[r];
            }
        }
    }
}

// Correct-but-slow fallback if d_ws can't hold the packed basis (346 KB).
__global__ void stft_naive(const float* __restrict__ sig,
                           const float* __restrict__ basis,
                           float* __restrict__ out) {
    long idx = (long)blockIdx.x * 256 + threadIdx.x;
    if (idx >= (long)NROWS * N_FRAMES) return;
    int row = (int)(idx / N_FRAMES);
    int tt = (int)(idx % N_FRAMES);
    long s0 = (long)tt * HOP - PAD;
    float acc = 0.0f;
    for (int n = 0; n < NTAPS; ++n) {
        long s = s0 + n;
        float x = (s >= 0 && s < (long)T_SIG) ? sig[s] : 0.0f;
        acc = fmaf(x, basis[row * NTAPS + n], acc);
    }
    out[idx] = acc;
}

extern "C" void kernel_launch(void* const* d_in, const int* in_sizes, int n_in,
                              void* d_out, int out_size, void* d_ws, size_t ws_size,
                              hipStream_t stream) {
    (void)in_sizes; (void)n_in; (void)out_size;
    const float* sig = (const float*)d_in[0];
    const float* basis = (const float*)d_in[1];
    float* out = (float*)d_out;
    const size_t need = (size_t)MT * KS * 64 * 8 * sizeof(unsigned short); // 346112 B
    if (ws_size >= need) {
        unsigned short* packed = (unsigned short*)d_ws;
        stft_prep<<<(MT * KS * 64 + 255) / 256, 256, 0, stream>>>(basis, packed);
        const int nblk = (N_FRAMES + FPB - 1) / FPB; // 938
        stft_mfma<<<nblk, THREADS, 0, stream>>>(sig, packed, out);
    } else {
        long total = (long)NROWS * N_FRAMES;
        stft_naive<<<(int)((total + 255) / 256), 256, 0, stream>>>(sig, basis, out);
    }
}

// Round 3
// 65.397 us; speedup vs baseline: 2.1695x; 2.1695x over previous
//
#include <hip/hip_runtime.h>

// ---- problem constants ----
#define HOP 160
#define NROWS 402            // 2*CUT
#define NTAPS 400            // N_FFT
#define T_SIG 9600000
#define N_FRAMES 60001
#define PAD 200              // CUT-1

// ---- tiling ----
#define MT 13                // 13 m-tiles * 32 rows = 416 (rows padded)
#define KS 26                // 26 k-steps * 16 taps = 416 (taps padded)
#define FPB 128              // frames per block (4 waves * 32)
#define MSPLIT 3             // m-tiles split across blocks: 5+4+4
#define NBT ((N_FRAMES + FPB - 1) / FPB)  // 469 frame-blocks
#define SPAN (127*HOP + 416) // 20736 signal floats staged per block
#define SPAN4 (SPAN/4)
#define LDSE 21776           // padded bf16 elems: 20736 + 8 per 160 block

typedef __bf16 bf16x8 __attribute__((ext_vector_type(8)));
typedef float f32x16 __attribute__((ext_vector_type(16)));
typedef unsigned short u16x8 __attribute__((ext_vector_type(8)));
typedef unsigned short u16x4 __attribute__((ext_vector_type(4)));

__device__ __forceinline__ unsigned short f2bf(float f) {
    // round-to-nearest-even fp32 -> bf16 (inputs are finite)
    unsigned int u = __builtin_bit_cast(unsigned int, f);
    u += 0x7fffu + ((u >> 16) & 1u);
    return (unsigned short)(u >> 16);
}

// Pack basis fp32[402][400] -> bf16 in exact per-fragment lane order:
// packed[((mt*KS+ks)*64 + lane)*8 + i] = bf16(basis[mt*32+(lane&31)][ks*16+8*(lane>>5)+i])
__global__ void stft_prep(const float* __restrict__ basis,
                          unsigned short* __restrict__ packed) {
    int tid = blockIdx.x * 256 + threadIdx.x;
    if (tid >= MT * KS * 64) return;
    int lane = tid & 63;
    int frag = tid >> 6;
    int ks = frag % KS;
    int mt = frag / KS;
    int row = mt * 32 + (lane & 31);
    int colb = ks * 16 + (lane >> 5) * 8;
    u16x8 v;
#pragma unroll
    for (int i = 0; i < 8; ++i) {
        int col = colb + i;
        float f = (row < NROWS && col < NTAPS) ? basis[row * NTAPS + col] : 0.0f;
        v[i] = f2bf(f);
    }
    *reinterpret_cast<u16x8*>(packed + (size_t)tid * 8) = v;
}

// C[row][t] = sum_c basis[row][c] * sig[t*160 + c - 200]
// Grid = NBT x MSPLIT. Block (bt, bm): frames bt*128..+128, m-tiles slice bm.
// 4 waves, each owns 32 frames, lockstep over the slice's m-tiles.
__launch_bounds__(256, 3)
__global__ void stft_mfma(const float* __restrict__ sig,
                          const unsigned short* __restrict__ packedA,
                          float* __restrict__ out) {
    // bf16 signal tile, +8 elems per 160 so frame-stride ds_read_b128 is
    // only 2-way bank aliased (free).
    __shared__ unsigned short sl[LDSE];
    const int tid = threadIdx.x;
    const int bt = blockIdx.x % NBT;   // frame-block (consecutive bids share signal)
    const int bm = blockIdx.x / NBT;   // m-slice
    const long sbase = (long)bt * (FPB * HOP) - PAD;

    // stage signal span -> bf16 LDS (coalesced float4, edge-guarded)
    for (int idx = tid; idx < SPAN4; idx += 256) {
        const int e = idx * 4;
        const long g0 = sbase + e;
        float4 v;
        if (g0 >= 0 && g0 + 4 <= (long)T_SIG) {
            v = *reinterpret_cast<const float4*>(sig + g0);
        } else {
            v.x = (g0 + 0 >= 0 && g0 + 0 < (long)T_SIG) ? sig[g0 + 0] : 0.0f;
            v.y = (g0 + 1 >= 0 && g0 + 1 < (long)T_SIG) ? sig[g0 + 1] : 0.0f;
            v.z = (g0 + 2 >= 0 && g0 + 2 < (long)T_SIG) ? sig[g0 + 2] : 0.0f;
            v.w = (g0 + 3 >= 0 && g0 + 3 < (long)T_SIG) ? sig[g0 + 3] : 0.0f;
        }
        u16x4 s;
        s[0] = f2bf(v.x); s[1] = f2bf(v.y); s[2] = f2bf(v.z); s[3] = f2bf(v.w);
        const int pos = e + 8 * (e / 160);  // 4-chunk never crosses a 160 block
        *reinterpret_cast<u16x4*>(&sl[pos]) = s;
    }
    __syncthreads();

    const int lane = tid & 63;
    const int w = tid >> 6;        // wave id, each wave owns 32 frames
    const int l31 = lane & 31;
    const int g = lane >> 5;       // k-group
    const int lf = w * 32 + l31;   // local frame 0..127
    const long t = (long)bt * FPB + lf;

    // m-slice: bm=0 -> {0..4}, bm=1 -> {5..8}, bm=2 -> {9..12}
    const int mt0 = (bm == 0) ? 0 : 5 + 4 * (bm - 1);
    const int mtN = (bm == 0) ? 5 : 4;

    // B-frag LDS base: 8 contiguous bf16 at lf*168 + g*8 + (ks*16 + 8*(ks/10))
    const unsigned short* bbase = &sl[lf * 168 + g * 8];
    const int rowg = 4 * g;

#pragma unroll 1
    for (int mi = 0; mi < mtN; ++mi) {
        const int mt = mt0 + mi;
        f32x16 acc = {0,0,0,0,0,0,0,0,0,0,0,0,0,0,0,0};
        const unsigned short* pA = packedA + ((size_t)(mt * KS) * 64 + lane) * 8;
#pragma unroll
        for (int ks = 0; ks < KS; ++ks) {
            const bf16x8 a = *reinterpret_cast<const bf16x8*>(pA + (size_t)ks * 64 * 8);
            const bf16x8 b = *reinterpret_cast<const bf16x8*>(bbase + ks * 16 + 8 * (ks / 10));
            acc = __builtin_amdgcn_mfma_f32_32x32x16_bf16(a, b, acc, 0, 0, 0);
        }
        if (t < N_FRAMES) {
            const int rb = mt * 32 + rowg;
#pragma unroll
            for (int r = 0; r < 16; ++r) {
                // HW-verified C/D map: row=(r&3)+8*(r>>2)+4*(lane>>5), col=lane&31
                const int row = rb + (r & 3) + 8 * (r >> 2);
                if (row < NROWS) out[(long)row * N_FRAMES + t] = acc[r];
            }
        }
        __syncthreads(); // keep waves' A-streams converged (L1-hot)
    }
}

// Correct-but-slow fallback if d_ws can't hold the packed basis (346 KB).
__global__ void stft_naive(const float* __restrict__ sig,
                           const float* __restrict__ basis,
                           float* __restrict__ out) {
    long idx = (long)blockIdx.x * 256 + threadIdx.x;
    if (idx >= (long)NROWS * N_FRAMES) return;
    int row = (int)(idx / N_FRAMES);
    int tt = (int)(idx % N_FRAMES);
    long s0 = (long)tt * HOP - PAD;
    float acc = 0.0f;
    for (int n = 0; n < NTAPS; ++n) {
        long s = s0 + n;
        float x = (s >= 0 && s < (long)T_SIG) ? sig[s] : 0.0f;
        acc = fmaf(x, basis[row * NTAPS + n], acc);
    }
    out[idx] = acc;
}

extern "C" void kernel_launch(void* const* d_in, const int* in_sizes, int n_in,
                              void* d_out, int out_size, void* d_ws, size_t ws_size,
                              hipStream_t stream) {
    (void)in_sizes; (void)n_in; (void)out_size;
    const float* sig = (const float*)d_in[0];
    const float* basis = (const float*)d_in[1];
    float* out = (float*)d_out;
    const size_t need = (size_t)MT * KS * 64 * 8 * sizeof(unsigned short); // 346112 B
    if (ws_size >= need) {
        unsigned short* packed = (unsigned short*)d_ws;
        stft_prep<<<(MT * KS * 64 + 255) / 256, 256, 0, stream>>>(basis, packed);
        stft_mfma<<<NBT * MSPLIT, 256, 0, stream>>>(sig, packed, out);
    } else {
        long total = (long)NROWS * N_FRAMES;
        stft_naive<<<(int)((total + 255) / 256), 256, 0, stream>>>(sig, basis, out);
    }
}